// Round 2
// baseline (222.097 us; speedup 1.0000x reference)
//
#include <hip/hip_runtime.h>

// SoftPerspectiveShader: barycentric texture sampling + softmax RGB blend.
// N=4, H=W=512, K=8, F=200000. One thread per pixel.
//
// R1 (prev session): gate the face_colors gather on weight magnitude. zbuf is
// sorted, so exp((z_inv - z_max)/1e-4) underflows unless z_inv is within
// ~1.2e-3 of z_max -> ~1.01 gathered fragments/pixel instead of 8.
//
// R2: kernel ran at ~1 TB/s = 15% of achievable HBM BW on fully-coalesced
// streams -> latency/occupancy-bound, not BW-bound.
//  (a) Defer bary loads into the gate: only the ~1 passing fragment needs its
//      12 B of barycentrics (-24 live VGPRs, -6 VMEM) -> target <=64 VGPRs
//      for 8 waves/SIMD instead of 4.
//  (b) Nontemporal hints on all single-use streams + output store so the
//      7.2 MB face_colors table stays L2-resident for the random gather.
//  (c) Gather as dwordx4 x2 + dword (36 B memcpy) instead of 9 scalar loads.
//
// R3: fix compile — __builtin_nontemporal_load/store needs native clang
// ext_vector_type, not HIP_vector_type (int4/float4 are class templates).

#define KFRAG 8

typedef int   ivec4 __attribute__((ext_vector_type(4)));
typedef float fvec4 __attribute__((ext_vector_type(4)));

__global__ __launch_bounds__(256) void soft_shader_kernel(
    const int*   __restrict__ p2f,         // [NP, 8]
    const float* __restrict__ bary,        // [NP, 8, 3]
    const float* __restrict__ zbuf,        // [NP, 8]
    const float* __restrict__ dists,       // [NP, 8]
    const float* __restrict__ face_colors, // [F, 3, 3]
    float*       __restrict__ out,         // [NP, 4]
    int NP)
{
    constexpr float SIGMA_INV = 1.0f / 1e-4f;
    constexpr float GAMMA_INV = 1.0f / 1e-4f;
    constexpr float EPS    = 1e-10f;
    constexpr float ZNEAR  = 1.0f;
    constexpr float ZFAR   = 100.0f;
    constexpr float ZSCALE = 1.0f / (ZFAR - ZNEAR);
    // exp((zinv-zmax)*1e4) < 1e-5 for zinv-zmax < -1.15e-3: contribution
    // < 1e-5 of normalized weight mass — far under the check threshold.
    constexpr float ZCUT = -1.2e-3f;

    int p = blockIdx.x * blockDim.x + threadIdx.x;
    if (p >= NP) return;

    // ---- coalesced single-use streams: nontemporal so face_colors keeps L2 ----
    const ivec4* p2f4 = (const ivec4*)p2f + (size_t)p * 2;
    ivec4 f0 = __builtin_nontemporal_load(p2f4 + 0);
    ivec4 f1 = __builtin_nontemporal_load(p2f4 + 1);

    const fvec4* zb4 = (const fvec4*)zbuf + (size_t)p * 2;
    fvec4 z0 = __builtin_nontemporal_load(zb4 + 0);
    fvec4 z1 = __builtin_nontemporal_load(zb4 + 1);

    const fvec4* dd4 = (const fvec4*)dists + (size_t)p * 2;
    fvec4 d0 = __builtin_nontemporal_load(dd4 + 0);
    fvec4 d1 = __builtin_nontemporal_load(dd4 + 1);

    int   fid[KFRAG] = {f0.x, f0.y, f0.z, f0.w, f1.x, f1.y, f1.z, f1.w};
    float zb[KFRAG]  = {z0.x, z0.y, z0.z, z0.w, z1.x, z1.y, z1.z, z1.w};
    float dd[KFRAG]  = {d0.x, d0.y, d0.z, d0.w, d1.x, d1.y, d1.z, d1.w};

    // ---- z_inv + running max (zbuf sorted ascending -> zmax is first valid) ----
    float zinv[KFRAG];
    float zmax = EPS;
#pragma unroll
    for (int k = 0; k < KFRAG; ++k) {
        float m = (fid[k] >= 0) ? 1.0f : 0.0f;
        zinv[k] = m * ((ZFAR - zb[k]) * ZSCALE);
        zmax = fmaxf(zmax, zinv[k]);
    }

    float delta = fmaxf(__expf((EPS - zmax) * GAMMA_INV), EPS);
    float denom = delta;
    float r = 0.0f, g = 0.0f, b = 0.0f;
    float keep = 1.0f; // prod(1 - prob) = 1 - alpha

#pragma unroll
    for (int k = 0; k < KFRAG; ++k) {
        if (fid[k] >= 0) {
            // sigmoid(-d/sigma) = 1/(1+exp(d/sigma))
            float pr = 1.0f / (1.0f + __expf(dd[k] * SIGMA_INV));
            keep *= (1.0f - pr);
            if (zinv[k] - zmax > ZCUT) {
                float w = pr * __expf((zinv[k] - zmax) * GAMMA_INV);

                // gated bary read: 12 B, only for the ~1 passing fragment
                const float* bp = bary + (size_t)p * (KFRAG * 3) + k * 3;
                float b0 = bp[0], b1 = bp[1], b2 = bp[2];

                // gated gather: 36 B as dwordx4 x2 + dword (dword-aligned ok)
                const float* fc = face_colors + (size_t)fid[k] * 9;
                float fcv[9];
                __builtin_memcpy(fcv, fc, 9 * sizeof(float));

                float tr = fmaf(b0, fcv[0], fmaf(b1, fcv[3], b2 * fcv[6]));
                float tg = fmaf(b0, fcv[1], fmaf(b1, fcv[4], b2 * fcv[7]));
                float tb = fmaf(b0, fcv[2], fmaf(b1, fcv[5], b2 * fcv[8]));

                denom += w;
                r = fmaf(w, tr, r);
                g = fmaf(w, tg, g);
                b = fmaf(w, tb, b);
            }
        }
    }

    float inv = 1.0f / denom;
    fvec4 o;
    o.x = (r + delta) * inv; // background = (1,1,1): + delta*1/denom
    o.y = (g + delta) * inv;
    o.z = (b + delta) * inv;
    o.w = keep;
    __builtin_nontemporal_store(o, (fvec4*)out + p);
}

extern "C" void kernel_launch(void* const* d_in, const int* in_sizes, int n_in,
                              void* d_out, int out_size, void* d_ws, size_t ws_size,
                              hipStream_t stream) {
    const int*   p2f         = (const int*)d_in[0];
    const float* bary        = (const float*)d_in[1];
    const float* zbuf        = (const float*)d_in[2];
    const float* dists       = (const float*)d_in[3];
    const float* face_colors = (const float*)d_in[4];
    float* out = (float*)d_out;

    int NP = in_sizes[0] / KFRAG; // N*H*W pixels
    int block = 256;
    int grid = (NP + block - 1) / block;
    soft_shader_kernel<<<grid, block, 0, stream>>>(
        p2f, bary, zbuf, dists, face_colors, out, NP);
}